// Round 5
// baseline (460.004 us; speedup 1.0000x reference)
//
#include <hip/hip_runtime.h>

#define NTOK 8192
#define D 4096
#define CH 1024

typedef __attribute__((ext_vector_type(8))) short short8v;
typedef __attribute__((ext_vector_type(4))) float float4v;
typedef __attribute__((ext_vector_type(4))) unsigned short ushort4v;
typedef __attribute__((ext_vector_type(8))) unsigned short ushort8v;

static __device__ __forceinline__ unsigned short f2bf(float f) {
  unsigned int u = __float_as_uint(f);
  u += 0x7fff + ((u >> 16) & 1);   // round-to-nearest-even
  return (unsigned short)(u >> 16);
}

static __device__ __forceinline__ float bf2f(unsigned short u) {
  return __uint_as_float(((unsigned int)u) << 16);
}

static __device__ __forceinline__ void async_cp16(const void* g, void* l) {
  __builtin_amdgcn_global_load_lds((__attribute__((address_space(1))) void*)g,
                                   (__attribute__((address_space(3))) void*)l,
                                   16, 0, 0);
}

// ---------------------------------------------------------------------------
// Kernel 0: weight prep. Wg = bf16[32][4096] gate weights with rms_w folded
// (rows 24..31 zero); Wb = bf16 Wsub. ~3 us.
// ---------------------------------------------------------------------------
__global__ __launch_bounds__(256) void prep_kernel(
    const float* __restrict__ Wpre, const float* __restrict__ Wpost,
    const float* __restrict__ Wres, const float* __restrict__ rms_w,
    const float* __restrict__ Wsub, unsigned short* __restrict__ Wg,
    unsigned short* __restrict__ Wb) {
  const int bid = blockIdx.x;
  if (bid < 2048) {
    int i = bid * 512 + threadIdx.x * 2;
    float2 v = *(const float2*)(Wsub + i);
    unsigned int packed = (unsigned int)f2bf(v.x) | ((unsigned int)f2bf(v.y) << 16);
    *(unsigned int*)(Wb + i) = packed;
  } else {
    int j = (bid - 2048) * 512 + threadIdx.x * 2;
    int g = j >> 12;
    int k = j & 4095;
    float2 r = *(const float2*)(rms_w + k);
    float2 wv;
    if (g < 4)       wv = *(const float2*)(Wpre + g * 4096 + k);
    else if (g < 8)  wv = *(const float2*)(Wpost + (g - 4) * 4096 + k);
    else if (g < 24) wv = *(const float2*)(Wres + (g - 8) * 4096 + k);
    else             { wv.x = 0.f; wv.y = 0.f; }
    unsigned int packed = (unsigned int)f2bf(wv.x * r.x) |
                          ((unsigned int)f2bf(wv.y * r.y) << 16);
    *(unsigned int*)(Wg + g * 4096 + k) = packed;
  }
}

// ---------------------------------------------------------------------------
// Kernel 1 v6: MFMA projection, residency-first, SPILL-FREE.
//  - Round-4 lesson: the 64-VGPR half-1 register preload spilled to scratch
//    (WRITE_SIZE 17->189 MB) and cost 2x. Latency hiding must come from TLP
//    (4 blocks/CU x 4 waves, barrier-free phases), not register pipelines.
//  - 1024 blocks x 256 threads (4 waves), 8 tokens/block, LDS 38 KB.
//  - Wave w owns K strip [w*1024,(w+1)*1024) as two 512-halves through ONE
//    8 KB LDS buffer (same-wave DS ops are in-order -> safe reuse).
//  - Staging in 4-token groups: max 32 VGPRs of loads in flight.
//  - Phase B reads x fp32 from global (L3-resident re-read).
// ---------------------------------------------------------------------------
__global__ __launch_bounds__(256, 4) void gates_kernel(
    const float* __restrict__ x, const unsigned short* __restrict__ Wg,
    const float* __restrict__ bpre, const float* __restrict__ bpost,
    const float* __restrict__ bres, const float* __restrict__ apre,
    const float* __restrict__ apost, const float* __restrict__ ares,
    float* __restrict__ gates_out, unsigned short* __restrict__ xlayer) {
  __shared__ __align__(16) unsigned short xb[4][8][512];  // 32 KB strip halves
  __shared__ float pl[4][8][32];                          // 4 KB partials
  __shared__ float sqp[4][8];
  __shared__ float logits_lds[8][32];
  __shared__ float s_lds[8];
  __shared__ float hpre_lds[8][4];

  const int tid = threadIdx.x;
  const int lane = tid & 63;
  const int w = tid >> 6;               // 0..3 = K-strip owner
  const int tok0 = blockIdx.x * 8;

  const float* src = x + (size_t)tok0 * D + w * 1024 + lane * 8;
  float sqacc[8];
#pragma unroll
  for (int t = 0; t < 8; ++t) sqacc[t] = 0.f;

  float4v acc0 = {0.f, 0.f, 0.f, 0.f};
  float4v acc1 = {0.f, 0.f, 0.f, 0.f};
  const int arow = lane & 7;            // token (A rows 8..15 dup 0..7)
  const int apos = lane >> 4;           // k-subgroup
  const unsigned short* bb0 = Wg + (size_t)(lane & 15) * D + w * 1024 + apos * 8;
  const unsigned short* bb1 = bb0 + 16 * D;

#pragma unroll
  for (int h = 0; h < 2; ++h) {
    // ---- stage half h in two 4-token groups (<=8 loads / 32 VGPRs in flight)
#pragma unroll
    for (int tg = 0; tg < 2; ++tg) {
      float4 a4[4], b4[4];
#pragma unroll
      for (int i = 0; i < 4; ++i) {
        const float* s = src + (size_t)(tg * 4 + i) * D + h * 512;
        a4[i] = *(const float4*)s;
        b4[i] = *(const float4*)(s + 4);
      }
#pragma unroll
      for (int i = 0; i < 4; ++i) {
        const int t = tg * 4 + i;
        sqacc[t] += a4[i].x * a4[i].x + a4[i].y * a4[i].y + a4[i].z * a4[i].z +
                    a4[i].w * a4[i].w + b4[i].x * b4[i].x + b4[i].y * b4[i].y +
                    b4[i].z * b4[i].z + b4[i].w * b4[i].w;
        ushort8v p;
        p[0] = f2bf(a4[i].x); p[1] = f2bf(a4[i].y);
        p[2] = f2bf(a4[i].z); p[3] = f2bf(a4[i].w);
        p[4] = f2bf(b4[i].x); p[5] = f2bf(b4[i].y);
        p[6] = f2bf(b4[i].z); p[7] = f2bf(b4[i].w);
        *(ushort8v*)(&xb[w][t][(lane ^ t) * 8]) = p;
      }
    }
    asm volatile("s_waitcnt lgkmcnt(0)" ::: "memory");
    __builtin_amdgcn_sched_barrier(0);

    // ---- MFMA half h (B-frags stream from L2-resident Wg)
#pragma unroll
    for (int ks = 0; ks < 16; ++ks) {
      short8v a = *(const short8v*)(&xb[w][arow][((ks * 4 + apos) ^ arow) * 8]);
      short8v b0v = *(const short8v*)(bb0 + h * 512 + ks * 32);
      short8v b1v = *(const short8v*)(bb1 + h * 512 + ks * 32);
      acc0 = __builtin_amdgcn_mfma_f32_16x16x32_bf16(a, b0v, acc0, 0, 0, 0);
      acc1 = __builtin_amdgcn_mfma_f32_16x16x32_bf16(a, b1v, acc1, 0, 0, 0);
    }
    // same-wave DS is in-order: half-1 writes cannot pass half-0 reads
  }

  // ---- per-wave reductions -> LDS
#pragma unroll
  for (int t = 0; t < 8; ++t) {
    float v = sqacc[t];
    for (int off = 32; off > 0; off >>= 1) v += __shfl_xor(v, off, 64);
    if (lane == 0) sqp[w][t] = v;
  }
  if (lane < 32) {
    const int tr = (lane >> 4) * 4;
    const int gc = lane & 15;
#pragma unroll
    for (int r = 0; r < 4; ++r) {
      pl[w][tr + r][gc] = acc0[r];
      pl[w][tr + r][16 + gc] = acc1[r];
    }
  }
  __syncthreads();

  // ---- cross-wave reduce (all 256 threads)
  {
    const int t = tid >> 5, g = tid & 31;
    logits_lds[t][g] = pl[0][t][g] + pl[1][t][g] + pl[2][t][g] + pl[3][t][g];
  }
  __syncthreads();

  // ---- per-token scalar math (threads 0..7): rms scale + sigmoids
  if (tid < 8) {
    const int t = tid;
    float sq = sqp[0][t] + sqp[1][t] + sqp[2][t] + sqp[3][t];
    float s = rsqrtf(sq * (1.0f / 4096.0f) + 1e-8f);
    s_lds[t] = s;
    float a_pre = apre[0], a_post = apost[0];

    float hp[4];
    float sum_p = 1e-6f;
#pragma unroll
    for (int i = 0; i < 4; ++i) {
      float z = a_pre * (s * logits_lds[t][i]) + bpre[i];
      hp[i] = 1.0f / (1.0f + __expf(-z));
      sum_p += hp[i];
    }
    float inv_p = 1.0f / sum_p;
#pragma unroll
    for (int i = 0; i < 4; ++i) hpre_lds[t][i] = hp[i] * inv_p;

    float* go = gates_out + (size_t)(tok0 + t) * 20;
    float hq[4];
    float sum_q = 1e-6f;
#pragma unroll
    for (int i = 0; i < 4; ++i) {
      float z = a_post * (s * logits_lds[t][4 + i]) + bpost[i];
      hq[i] = 2.0f / (1.0f + __expf(-z));
      sum_q += hq[i];
    }
    float inv_q = 1.0f / sum_q;
#pragma unroll
    for (int i = 0; i < 4; ++i) go[i] = hq[i] * inv_q;
  }
  __syncthreads();

  // ---- sinkhorn (wave 0, lanes<32: 8 tok x 4 rows); waves 1..3 go straight
  //      to phase B
  if (w == 0 && lane < 32) {
    const int t = lane >> 2;
    const int r = lane & 3;
    const float s = s_lds[t];
    const float a_res = ares[0];
    float Zrow[4], Zcol[4];
#pragma unroll
    for (int j = 0; j < 4; ++j) {
      Zrow[j] = (a_res * (s * logits_lds[t][8 + r * 4 + j]) + bres[r * 4 + j]) * 20.0f;
      Zcol[j] = (a_res * (s * logits_lds[t][8 + j * 4 + r]) + bres[j * 4 + r]) * 20.0f;
    }
    float u = 0.f, v = 0.f;
    const int base = t << 2;
    for (int it = 0; it < 20; ++it) {
      float v0 = __shfl(v, base + 0, 64), v1 = __shfl(v, base + 1, 64);
      float v2 = __shfl(v, base + 2, 64), v3 = __shfl(v, base + 3, 64);
      float a0 = Zrow[0] + v0, a1 = Zrow[1] + v1, a2 = Zrow[2] + v2, a3 = Zrow[3] + v3;
      float m = fmaxf(fmaxf(a0, a1), fmaxf(a2, a3));
      float sm = __expf(a0 - m) + __expf(a1 - m) + __expf(a2 - m) + __expf(a3 - m);
      u = -(m + __logf(sm));
      float u0 = __shfl(u, base + 0, 64), u1 = __shfl(u, base + 1, 64);
      float u2 = __shfl(u, base + 2, 64), u3 = __shfl(u, base + 3, 64);
      float b0 = Zcol[0] + u0, b1 = Zcol[1] + u1, b2 = Zcol[2] + u2, b3 = Zcol[3] + u3;
      float m2 = fmaxf(fmaxf(b0, b1), fmaxf(b2, b3));
      float sm2 = __expf(b0 - m2) + __expf(b1 - m2) + __expf(b2 - m2) + __expf(b3 - m2);
      v = -(m2 + __logf(sm2));
    }
    float v0 = __shfl(v, base + 0, 64), v1 = __shfl(v, base + 1, 64);
    float v2 = __shfl(v, base + 2, 64), v3 = __shfl(v, base + 3, 64);
    float* go = gates_out + (size_t)(tok0 + t) * 20;
    go[4 + r * 4 + 0] = __expf(Zrow[0] + u + v0);
    go[4 + r * 4 + 1] = __expf(Zrow[1] + u + v1);
    go[4 + r * 4 + 2] = __expf(Zrow[2] + u + v2);
    go[4 + r * 4 + 3] = __expf(Zrow[3] + u + v3);
  }

  // ---- phase B: x_layer from global fp32 x (L3-warm). Iteration t = token;
  //      256 threads cover the 1024 channels as float4.
#pragma unroll 2
  for (int t = 0; t < 8; ++t) {
    const float h0 = hpre_lds[t][0], h1 = hpre_lds[t][1];
    const float h2 = hpre_lds[t][2], h3 = hpre_lds[t][3];
    const size_t xbase = (size_t)(tok0 + t) * D + tid * 4;
    float4 x0 = *(const float4*)(x + xbase);
    float4 x1 = *(const float4*)(x + xbase + 1024);
    float4 x2 = *(const float4*)(x + xbase + 2048);
    float4 x3 = *(const float4*)(x + xbase + 3072);
    ushort4v o;
    o.x = f2bf(h0 * x0.x + h1 * x1.x + h2 * x2.x + h3 * x3.x);
    o.y = f2bf(h0 * x0.y + h1 * x1.y + h2 * x2.y + h3 * x3.y);
    o.z = f2bf(h0 * x0.z + h1 * x1.z + h2 * x2.z + h3 * x3.z);
    o.w = f2bf(h0 * x0.w + h1 * x1.w + h2 * x2.w + h3 * x3.w);
    *(ushort4v*)(xlayer + (size_t)(tok0 + t) * CH + tid * 4) = o;
  }
}

// ---------------------------------------------------------------------------
// Kernel 2 v3 (unchanged from round 4): y = x_layer @ W_sub^T (bf16 MFMA,
// 128x128, BK=64, dbuf); epilogue transposes acc through the dead staging
// buffer so all epilogue VMEM is float4.
// ---------------------------------------------------------------------------
__global__ __launch_bounds__(256, 2) void gemm_epi(
    const unsigned short* __restrict__ A,   // x_layer bf16 [8192][1024]
    const unsigned short* __restrict__ B,   // W_sub  bf16 [1024][1024]
    const float* __restrict__ x,            // x_streams fp32
    const float* __restrict__ gates,        // [8192][20]: Hpost_w[4], Hres[16]
    float* __restrict__ out) {
  __shared__ __align__(16) unsigned short stg[32768];  // 64 KB: [buf][A|B]
  __shared__ float hpost_sm[128][4];
  __shared__ float hres_sm[128][16];

  const int tid = threadIdx.x;
  const int lane = tid & 63;
  const int w = tid >> 6;
  const int n0 = blockIdx.x * 128;
  const int m0 = blockIdx.y * 128;

  {
    const int r = tid >> 1, half = tid & 1;
    const float* gp = gates + (size_t)(m0 + r) * 20 + half * 10;
#pragma unroll
    for (int j = 0; j < 10; ++j) {
      int jj = half * 10 + j;
      float v = gp[j];
      if (jj < 4) hpost_sm[r][jj] = v;
      else        hres_sm[r][jj - 4] = v;
    }
  }

  float4v accf[4][4];
#pragma unroll
  for (int mi = 0; mi < 4; ++mi)
#pragma unroll
    for (int ni = 0; ni < 4; ++ni) {
      accf[mi][ni].x = 0.f; accf[mi][ni].y = 0.f;
      accf[mi][ni].z = 0.f; accf[mi][ni].w = 0.f;
    }

  const int wm = (w >> 1) * 64;
  const int wn = (w & 1) * 64;
  const int srow = lane >> 3;
  const int sslot = lane & 7;

#define STAGE(KT, BUF)                                                        \
  {                                                                           \
    const int k0s = (KT) * 64;                                                \
    unsigned short* As = stg + (BUF) * 8192;                                  \
    unsigned short* Bs = stg + 16384 + (BUF) * 8192;                          \
    _Pragma("unroll")                                                         \
    for (int i = 0; i < 4; ++i) {                                             \
      int chunk = w * 4 + i;                                                  \
      int row = chunk * 8 + srow;                                             \
      int qg = sslot ^ (row & 7);                                             \
      async_cp16(A + (size_t)(m0 + row) * 1024 + k0s + qg * 8,                \
                 (void*)(As + chunk * 512));                                  \
      async_cp16(B + (size_t)(n0 + row) * 1024 + k0s + qg * 8,                \
                 (void*)(Bs + chunk * 512));                                  \
    }                                                                         \
  }

  STAGE(0, 0);
  __syncthreads();

  for (int kt = 0; kt < 16; ++kt) {
    const int cur = kt & 1;
    if (kt < 15) STAGE(kt + 1, cur ^ 1);
    const unsigned short* As = stg + cur * 8192;
    const unsigned short* Bs = stg + 16384 + cur * 8192;
#pragma unroll
    for (int kk = 0; kk < 2; ++kk) {
      short8v a[4], b[4];
#pragma unroll
      for (int mi = 0; mi < 4; ++mi) {
        int row = wm + mi * 16 + (lane & 15);
        int q = (kk * 4 + (lane >> 4)) ^ (row & 7);
        a[mi] = *(const short8v*)(As + row * 64 + q * 8);
      }
#pragma unroll
      for (int ni = 0; ni < 4; ++ni) {
        int row = wn + ni * 16 + (lane & 15);
        int q = (kk * 4 + (lane >> 4)) ^ (row & 7);
        b[ni] = *(const short8v*)(Bs + row * 64 + q * 8);
      }
#pragma unroll
      for (int mi = 0; mi < 4; ++mi)
#pragma unroll
        for (int ni = 0; ni < 4; ++ni)
          accf[mi][ni] = __builtin_amdgcn_mfma_f32_16x16x32_bf16(
              a[mi], b[ni], accf[mi][ni], 0, 0, 0);
    }
    __syncthreads();
  }

  // ---- epilogue: per-wave transpose through dead staging buffer, then
  //      fully-float4 x-read / out-write.
  float* mysc = (float*)stg + w * 1088;   // 16 rows x 68 floats per wave
  const int rg = (lane >> 4) * 4;         // acc row group
  const int cl = lane & 15;               // acc col
  const int erow = lane >> 2;             // epilogue row 0..15
  const int ec = lane & 3;                // epilogue col4 base
#pragma unroll
  for (int mi = 0; mi < 4; ++mi) {
#pragma unroll
    for (int ni = 0; ni < 4; ++ni)
#pragma unroll
      for (int r = 0; r < 4; ++r)
        mysc[(rg + r) * 68 + ni * 16 + cl] = accf[mi][ni][r];
    asm volatile("s_waitcnt lgkmcnt(0)" ::: "memory");

    const int row128 = wm + mi * 16 + erow;
    const size_t t = (size_t)(m0 + row128);
    const float4 hq = *(const float4*)(&hpost_sm[row128][0]);
    const float4 h0 = *(const float4*)(&hres_sm[row128][0]);
    const float4 h1 = *(const float4*)(&hres_sm[row128][4]);
    const float4 h2 = *(const float4*)(&hres_sm[row128][8]);
    const float4 h3 = *(const float4*)(&hres_sm[row128][12]);
#pragma unroll
    for (int s = 0; s < 4; ++s) {
      const int c4 = ec + s * 4;          // float4 col 0..15
      float4 y4 = *(const float4*)(&mysc[erow * 68 + c4 * 4]);
      const size_t xb_ = t * 4096 + n0 + wn + c4 * 4;
      float4 x0 = *(const float4*)(x + xb_);
      float4 x1 = *(const float4*)(x + xb_ + 1024);
      float4 x2 = *(const float4*)(x + xb_ + 2048);
      float4 x3 = *(const float4*)(x + xb_ + 3072);
      float4 rr;
      rr.x = x0.x * h0.x + x1.x * h0.y + x2.x * h0.z + x3.x * h0.w + hq.x * y4.x;
      rr.y = x0.y * h0.x + x1.y * h0.y + x2.y * h0.z + x3.y * h0.w + hq.x * y4.y;
      rr.z = x0.z * h0.x + x1.z * h0.y + x2.z * h0.z + x3.z * h0.w + hq.x * y4.z;
      rr.w = x0.w * h0.x + x1.w * h0.y + x2.w * h0.z + x3.w * h0.w + hq.x * y4.w;
      *(float4*)(out + xb_) = rr;
      rr.x = x0.x * h1.x + x1.x * h1.y + x2.x * h1.z + x3.x * h1.w + hq.y * y4.x;
      rr.y = x0.y * h1.x + x1.y * h1.y + x2.y * h1.z + x3.y * h1.w + hq.y * y4.y;
      rr.z = x0.z * h1.x + x1.z * h1.y + x2.z * h1.z + x3.z * h1.w + hq.y * y4.z;
      rr.w = x0.w * h1.x + x1.w * h1.y + x2.w * h1.z + x3.w * h1.w + hq.y * y4.w;
      *(float4*)(out + xb_ + 1024) = rr;
      rr.x = x0.x * h2.x + x1.x * h2.y + x2.x * h2.z + x3.x * h2.w + hq.z * y4.x;
      rr.y = x0.y * h2.x + x1.y * h2.y + x2.y * h2.z + x3.y * h2.w + hq.z * y4.y;
      rr.z = x0.z * h2.x + x1.z * h2.y + x2.z * h2.z + x3.z * h2.w + hq.z * y4.z;
      rr.w = x0.w * h2.x + x1.w * h2.y + x2.w * h2.z + x3.w * h2.w + hq.z * y4.w;
      *(float4*)(out + xb_ + 2048) = rr;
      rr.x = x0.x * h3.x + x1.x * h3.y + x2.x * h3.z + x3.x * h3.w + hq.w * y4.x;
      rr.y = x0.y * h3.x + x1.y * h3.y + x2.y * h3.z + x3.y * h3.w + hq.w * y4.y;
      rr.z = x0.z * h3.x + x1.z * h3.y + x2.z * h3.z + x3.z * h3.w + hq.w * y4.z;
      rr.w = x0.w * h3.x + x1.w * h3.y + x2.w * h3.z + x3.w * h3.w + hq.w * y4.w;
      *(float4*)(out + xb_ + 3072) = rr;
    }
    asm volatile("s_waitcnt lgkmcnt(0)" ::: "memory");  // reads done before next mi's writes
  }
}

extern "C" void kernel_launch(void* const* d_in, const int* in_sizes, int n_in,
                              void* d_out, int out_size, void* d_ws, size_t ws_size,
                              hipStream_t stream) {
  const float* x     = (const float*)d_in[0];
  const float* rms_w = (const float*)d_in[1];
  const float* Wpre  = (const float*)d_in[2];
  const float* Wpost = (const float*)d_in[3];
  const float* Wres  = (const float*)d_in[4];
  const float* bpre  = (const float*)d_in[5];
  const float* bpost = (const float*)d_in[6];
  const float* bres  = (const float*)d_in[7];
  const float* apre  = (const float*)d_in[8];
  const float* apost = (const float*)d_in[9];
  const float* ares  = (const float*)d_in[10];
  const float* Wsub  = (const float*)d_in[11];
  float* out = (float*)d_out;

  char* ws = (char*)d_ws;
  float* gates           = (float*)ws;                         // 640 KB
  unsigned short* Wb     = (unsigned short*)(ws + (1 << 20));  // 2 MB
  unsigned short* Wg     = (unsigned short*)(ws + (3 << 20));  // 256 KB
  unsigned short* xlayer = (unsigned short*)(ws + (4 << 20));  // 16 MB

  prep_kernel<<<2304, 256, 0, stream>>>(Wpre, Wpost, Wres, rms_w, Wsub, Wg, Wb);
  gates_kernel<<<1024, 256, 0, stream>>>(x, Wg, bpre, bpost, bres,
                                         apre, apost, ares, gates, xlayer);
  gemm_epi<<<dim3(8, 64), 256, 0, stream>>>(xlayer, Wb, x, gates, out);
}

// Round 6
// 367.723 us; speedup vs baseline: 1.2510x; 1.2510x over previous
//
#include <hip/hip_runtime.h>

#define NTOK 8192
#define D 4096
#define CH 1024

typedef __attribute__((ext_vector_type(8))) short short8v;
typedef __attribute__((ext_vector_type(4))) float float4v;
typedef __attribute__((ext_vector_type(4))) unsigned short ushort4v;
typedef __attribute__((ext_vector_type(8))) unsigned short ushort8v;

static __device__ __forceinline__ unsigned short f2bf(float f) {
  unsigned int u = __float_as_uint(f);
  u += 0x7fff + ((u >> 16) & 1);   // round-to-nearest-even
  return (unsigned short)(u >> 16);
}

static __device__ __forceinline__ float bf2f(unsigned short u) {
  return __uint_as_float(((unsigned int)u) << 16);
}

static __device__ __forceinline__ void async_cp16(const void* g, void* l) {
  __builtin_amdgcn_global_load_lds((__attribute__((address_space(1))) void*)g,
                                   (__attribute__((address_space(3))) void*)l,
                                   16, 0, 0);
}

// ---------------------------------------------------------------------------
// Kernel 0: weight prep. Wg = bf16[32][4096] gate weights with rms_w folded
// (rows 24..31 zero); Wb = bf16 Wsub. ~3 us.
// ---------------------------------------------------------------------------
__global__ __launch_bounds__(256) void prep_kernel(
    const float* __restrict__ Wpre, const float* __restrict__ Wpost,
    const float* __restrict__ Wres, const float* __restrict__ rms_w,
    const float* __restrict__ Wsub, unsigned short* __restrict__ Wg,
    unsigned short* __restrict__ Wb) {
  const int bid = blockIdx.x;
  if (bid < 2048) {
    int i = bid * 512 + threadIdx.x * 2;
    float2 v = *(const float2*)(Wsub + i);
    unsigned int packed = (unsigned int)f2bf(v.x) | ((unsigned int)f2bf(v.y) << 16);
    *(unsigned int*)(Wb + i) = packed;
  } else {
    int j = (bid - 2048) * 512 + threadIdx.x * 2;
    int g = j >> 12;
    int k = j & 4095;
    float2 r = *(const float2*)(rms_w + k);
    float2 wv;
    if (g < 4)       wv = *(const float2*)(Wpre + g * 4096 + k);
    else if (g < 8)  wv = *(const float2*)(Wpost + (g - 4) * 4096 + k);
    else if (g < 24) wv = *(const float2*)(Wres + (g - 8) * 4096 + k);
    else             { wv.x = 0.f; wv.y = 0.f; }
    unsigned int packed = (unsigned int)f2bf(wv.x * r.x) |
                          ((unsigned int)f2bf(wv.y * r.y) << 16);
    *(unsigned int*)(Wg + g * 4096 + k) = packed;
  }
}

// ---------------------------------------------------------------------------
// Kernel 1 v7: MFMA projection. ONLY change vs v6: __launch_bounds__(256,2).
//  - Round-5 lesson: (256,4) forces arch+accum regs <= 128 on the unified
//    gfx950 file; allocator split 64/64 and spilled ~680 B/thread to scratch
//    (WRITE_SIZE 197 MB). (256,2) lifts the cap; body needs ~100-128 regs,
//    LDS (38.4 KB) still limits residency to 4 blocks/CU.
// ---------------------------------------------------------------------------
__global__ __launch_bounds__(256, 2) void gates_kernel(
    const float* __restrict__ x, const unsigned short* __restrict__ Wg,
    const float* __restrict__ bpre, const float* __restrict__ bpost,
    const float* __restrict__ bres, const float* __restrict__ apre,
    const float* __restrict__ apost, const float* __restrict__ ares,
    float* __restrict__ gates_out, unsigned short* __restrict__ xlayer) {
  __shared__ __align__(16) unsigned short xb[4][8][512];  // 32 KB strip halves
  __shared__ float pl[4][8][32];                          // 4 KB partials
  __shared__ float sqp[4][8];
  __shared__ float logits_lds[8][32];
  __shared__ float s_lds[8];
  __shared__ float hpre_lds[8][4];

  const int tid = threadIdx.x;
  const int lane = tid & 63;
  const int w = tid >> 6;               // 0..3 = K-strip owner
  const int tok0 = blockIdx.x * 8;

  const float* src = x + (size_t)tok0 * D + w * 1024 + lane * 8;
  float sqacc[8];
#pragma unroll
  for (int t = 0; t < 8; ++t) sqacc[t] = 0.f;

  float4v acc0 = {0.f, 0.f, 0.f, 0.f};
  float4v acc1 = {0.f, 0.f, 0.f, 0.f};
  const int arow = lane & 7;            // token (A rows 8..15 dup 0..7)
  const int apos = lane >> 4;           // k-subgroup
  const unsigned short* bb0 = Wg + (size_t)(lane & 15) * D + w * 1024 + apos * 8;
  const unsigned short* bb1 = bb0 + 16 * D;

#pragma unroll
  for (int h = 0; h < 2; ++h) {
    // ---- stage half h in two 4-token groups (<=8 loads / 32 VGPRs in flight)
#pragma unroll
    for (int tg = 0; tg < 2; ++tg) {
      float4 a4[4], b4[4];
#pragma unroll
      for (int i = 0; i < 4; ++i) {
        const float* s = src + (size_t)(tg * 4 + i) * D + h * 512;
        a4[i] = *(const float4*)s;
        b4[i] = *(const float4*)(s + 4);
      }
#pragma unroll
      for (int i = 0; i < 4; ++i) {
        const int t = tg * 4 + i;
        sqacc[t] += a4[i].x * a4[i].x + a4[i].y * a4[i].y + a4[i].z * a4[i].z +
                    a4[i].w * a4[i].w + b4[i].x * b4[i].x + b4[i].y * b4[i].y +
                    b4[i].z * b4[i].z + b4[i].w * b4[i].w;
        ushort8v p;
        p[0] = f2bf(a4[i].x); p[1] = f2bf(a4[i].y);
        p[2] = f2bf(a4[i].z); p[3] = f2bf(a4[i].w);
        p[4] = f2bf(b4[i].x); p[5] = f2bf(b4[i].y);
        p[6] = f2bf(b4[i].z); p[7] = f2bf(b4[i].w);
        *(ushort8v*)(&xb[w][t][(lane ^ t) * 8]) = p;
      }
    }
    asm volatile("s_waitcnt lgkmcnt(0)" ::: "memory");
    __builtin_amdgcn_sched_barrier(0);

    // ---- MFMA half h (B-frags stream from L2-resident Wg)
#pragma unroll
    for (int ks = 0; ks < 16; ++ks) {
      short8v a = *(const short8v*)(&xb[w][arow][((ks * 4 + apos) ^ arow) * 8]);
      short8v b0v = *(const short8v*)(bb0 + h * 512 + ks * 32);
      short8v b1v = *(const short8v*)(bb1 + h * 512 + ks * 32);
      acc0 = __builtin_amdgcn_mfma_f32_16x16x32_bf16(a, b0v, acc0, 0, 0, 0);
      acc1 = __builtin_amdgcn_mfma_f32_16x16x32_bf16(a, b1v, acc1, 0, 0, 0);
    }
    // same-wave DS is in-order: half-1 writes cannot pass half-0 reads
  }

  // ---- per-wave reductions -> LDS
#pragma unroll
  for (int t = 0; t < 8; ++t) {
    float v = sqacc[t];
    for (int off = 32; off > 0; off >>= 1) v += __shfl_xor(v, off, 64);
    if (lane == 0) sqp[w][t] = v;
  }
  if (lane < 32) {
    const int tr = (lane >> 4) * 4;
    const int gc = lane & 15;
#pragma unroll
    for (int r = 0; r < 4; ++r) {
      pl[w][tr + r][gc] = acc0[r];
      pl[w][tr + r][16 + gc] = acc1[r];
    }
  }
  __syncthreads();

  // ---- cross-wave reduce (all 256 threads)
  {
    const int t = tid >> 5, g = tid & 31;
    logits_lds[t][g] = pl[0][t][g] + pl[1][t][g] + pl[2][t][g] + pl[3][t][g];
  }
  __syncthreads();

  // ---- per-token scalar math (threads 0..7): rms scale + sigmoids
  if (tid < 8) {
    const int t = tid;
    float sq = sqp[0][t] + sqp[1][t] + sqp[2][t] + sqp[3][t];
    float s = rsqrtf(sq * (1.0f / 4096.0f) + 1e-8f);
    s_lds[t] = s;
    float a_pre = apre[0], a_post = apost[0];

    float hp[4];
    float sum_p = 1e-6f;
#pragma unroll
    for (int i = 0; i < 4; ++i) {
      float z = a_pre * (s * logits_lds[t][i]) + bpre[i];
      hp[i] = 1.0f / (1.0f + __expf(-z));
      sum_p += hp[i];
    }
    float inv_p = 1.0f / sum_p;
#pragma unroll
    for (int i = 0; i < 4; ++i) hpre_lds[t][i] = hp[i] * inv_p;

    float* go = gates_out + (size_t)(tok0 + t) * 20;
    float hq[4];
    float sum_q = 1e-6f;
#pragma unroll
    for (int i = 0; i < 4; ++i) {
      float z = a_post * (s * logits_lds[t][4 + i]) + bpost[i];
      hq[i] = 2.0f / (1.0f + __expf(-z));
      sum_q += hq[i];
    }
    float inv_q = 1.0f / sum_q;
#pragma unroll
    for (int i = 0; i < 4; ++i) go[i] = hq[i] * inv_q;
  }
  __syncthreads();

  // ---- sinkhorn (wave 0, lanes<32: 8 tok x 4 rows); waves 1..3 go straight
  //      to phase B
  if (w == 0 && lane < 32) {
    const int t = lane >> 2;
    const int r = lane & 3;
    const float s = s_lds[t];
    const float a_res = ares[0];
    float Zrow[4], Zcol[4];
#pragma unroll
    for (int j = 0; j < 4; ++j) {
      Zrow[j] = (a_res * (s * logits_lds[t][8 + r * 4 + j]) + bres[r * 4 + j]) * 20.0f;
      Zcol[j] = (a_res * (s * logits_lds[t][8 + j * 4 + r]) + bres[j * 4 + r]) * 20.0f;
    }
    float u = 0.f, v = 0.f;
    const int base = t << 2;
    for (int it = 0; it < 20; ++it) {
      float v0 = __shfl(v, base + 0, 64), v1 = __shfl(v, base + 1, 64);
      float v2 = __shfl(v, base + 2, 64), v3 = __shfl(v, base + 3, 64);
      float a0 = Zrow[0] + v0, a1 = Zrow[1] + v1, a2 = Zrow[2] + v2, a3 = Zrow[3] + v3;
      float m = fmaxf(fmaxf(a0, a1), fmaxf(a2, a3));
      float sm = __expf(a0 - m) + __expf(a1 - m) + __expf(a2 - m) + __expf(a3 - m);
      u = -(m + __logf(sm));
      float u0 = __shfl(u, base + 0, 64), u1 = __shfl(u, base + 1, 64);
      float u2 = __shfl(u, base + 2, 64), u3 = __shfl(u, base + 3, 64);
      float b0 = Zcol[0] + u0, b1 = Zcol[1] + u1, b2 = Zcol[2] + u2, b3 = Zcol[3] + u3;
      float m2 = fmaxf(fmaxf(b0, b1), fmaxf(b2, b3));
      float sm2 = __expf(b0 - m2) + __expf(b1 - m2) + __expf(b2 - m2) + __expf(b3 - m2);
      v = -(m2 + __logf(sm2));
    }
    float v0 = __shfl(v, base + 0, 64), v1 = __shfl(v, base + 1, 64);
    float v2 = __shfl(v, base + 2, 64), v3 = __shfl(v, base + 3, 64);
    float* go = gates_out + (size_t)(tok0 + t) * 20;
    go[4 + r * 4 + 0] = __expf(Zrow[0] + u + v0);
    go[4 + r * 4 + 1] = __expf(Zrow[1] + u + v1);
    go[4 + r * 4 + 2] = __expf(Zrow[2] + u + v2);
    go[4 + r * 4 + 3] = __expf(Zrow[3] + u + v3);
  }

  // ---- phase B: x_layer from global fp32 x (L3-warm). Iteration t = token;
  //      256 threads cover the 1024 channels as float4.
#pragma unroll 2
  for (int t = 0; t < 8; ++t) {
    const float h0 = hpre_lds[t][0], h1 = hpre_lds[t][1];
    const float h2 = hpre_lds[t][2], h3 = hpre_lds[t][3];
    const size_t xbase = (size_t)(tok0 + t) * D + tid * 4;
    float4 x0 = *(const float4*)(x + xbase);
    float4 x1 = *(const float4*)(x + xbase + 1024);
    float4 x2 = *(const float4*)(x + xbase + 2048);
    float4 x3 = *(const float4*)(x + xbase + 3072);
    ushort4v o;
    o.x = f2bf(h0 * x0.x + h1 * x1.x + h2 * x2.x + h3 * x3.x);
    o.y = f2bf(h0 * x0.y + h1 * x1.y + h2 * x2.y + h3 * x3.y);
    o.z = f2bf(h0 * x0.z + h1 * x1.z + h2 * x2.z + h3 * x3.z);
    o.w = f2bf(h0 * x0.w + h1 * x1.w + h2 * x2.w + h3 * x3.w);
    *(ushort4v*)(xlayer + (size_t)(tok0 + t) * CH + tid * 4) = o;
  }
}

// ---------------------------------------------------------------------------
// Kernel 2 v3 (unchanged): y = x_layer @ W_sub^T (bf16 MFMA, 128x128, BK=64,
// dbuf); epilogue transposes acc through the dead staging buffer so all
// epilogue VMEM is float4.
// ---------------------------------------------------------------------------
__global__ __launch_bounds__(256, 2) void gemm_epi(
    const unsigned short* __restrict__ A,   // x_layer bf16 [8192][1024]
    const unsigned short* __restrict__ B,   // W_sub  bf16 [1024][1024]
    const float* __restrict__ x,            // x_streams fp32
    const float* __restrict__ gates,        // [8192][20]: Hpost_w[4], Hres[16]
    float* __restrict__ out) {
  __shared__ __align__(16) unsigned short stg[32768];  // 64 KB: [buf][A|B]
  __shared__ float hpost_sm[128][4];
  __shared__ float hres_sm[128][16];

  const int tid = threadIdx.x;
  const int lane = tid & 63;
  const int w = tid >> 6;
  const int n0 = blockIdx.x * 128;
  const int m0 = blockIdx.y * 128;

  {
    const int r = tid >> 1, half = tid & 1;
    const float* gp = gates + (size_t)(m0 + r) * 20 + half * 10;
#pragma unroll
    for (int j = 0; j < 10; ++j) {
      int jj = half * 10 + j;
      float v = gp[j];
      if (jj < 4) hpost_sm[r][jj] = v;
      else        hres_sm[r][jj - 4] = v;
    }
  }

  float4v accf[4][4];
#pragma unroll
  for (int mi = 0; mi < 4; ++mi)
#pragma unroll
    for (int ni = 0; ni < 4; ++ni) {
      accf[mi][ni].x = 0.f; accf[mi][ni].y = 0.f;
      accf[mi][ni].z = 0.f; accf[mi][ni].w = 0.f;
    }

  const int wm = (w >> 1) * 64;
  const int wn = (w & 1) * 64;
  const int srow = lane >> 3;
  const int sslot = lane & 7;

#define STAGE(KT, BUF)                                                        \
  {                                                                           \
    const int k0s = (KT) * 64;                                                \
    unsigned short* As = stg + (BUF) * 8192;                                  \
    unsigned short* Bs = stg + 16384 + (BUF) * 8192;                          \
    _Pragma("unroll")                                                         \
    for (int i = 0; i < 4; ++i) {                                             \
      int chunk = w * 4 + i;                                                  \
      int row = chunk * 8 + srow;                                             \
      int qg = sslot ^ (row & 7);                                             \
      async_cp16(A + (size_t)(m0 + row) * 1024 + k0s + qg * 8,                \
                 (void*)(As + chunk * 512));                                  \
      async_cp16(B + (size_t)(n0 + row) * 1024 + k0s + qg * 8,                \
                 (void*)(Bs + chunk * 512));                                  \
    }                                                                         \
  }

  STAGE(0, 0);
  __syncthreads();

  for (int kt = 0; kt < 16; ++kt) {
    const int cur = kt & 1;
    if (kt < 15) STAGE(kt + 1, cur ^ 1);
    const unsigned short* As = stg + cur * 8192;
    const unsigned short* Bs = stg + 16384 + cur * 8192;
#pragma unroll
    for (int kk = 0; kk < 2; ++kk) {
      short8v a[4], b[4];
#pragma unroll
      for (int mi = 0; mi < 4; ++mi) {
        int row = wm + mi * 16 + (lane & 15);
        int q = (kk * 4 + (lane >> 4)) ^ (row & 7);
        a[mi] = *(const short8v*)(As + row * 64 + q * 8);
      }
#pragma unroll
      for (int ni = 0; ni < 4; ++ni) {
        int row = wn + ni * 16 + (lane & 15);
        int q = (kk * 4 + (lane >> 4)) ^ (row & 7);
        b[ni] = *(const short8v*)(Bs + row * 64 + q * 8);
      }
#pragma unroll
      for (int mi = 0; mi < 4; ++mi)
#pragma unroll
        for (int ni = 0; ni < 4; ++ni)
          accf[mi][ni] = __builtin_amdgcn_mfma_f32_16x16x32_bf16(
              a[mi], b[ni], accf[mi][ni], 0, 0, 0);
    }
    __syncthreads();
  }

  // ---- epilogue: per-wave transpose through dead staging buffer, then
  //      fully-float4 x-read / out-write.
  float* mysc = (float*)stg + w * 1088;   // 16 rows x 68 floats per wave
  const int rg = (lane >> 4) * 4;         // acc row group
  const int cl = lane & 15;               // acc col
  const int erow = lane >> 2;             // epilogue row 0..15
  const int ec = lane & 3;                // epilogue col4 base
#pragma unroll
  for (int mi = 0; mi < 4; ++mi) {
#pragma unroll
    for (int ni = 0; ni < 4; ++ni)
#pragma unroll
      for (int r = 0; r < 4; ++r)
        mysc[(rg + r) * 68 + ni * 16 + cl] = accf[mi][ni][r];
    asm volatile("s_waitcnt lgkmcnt(0)" ::: "memory");

    const int row128 = wm + mi * 16 + erow;
    const size_t t = (size_t)(m0 + row128);
    const float4 hq = *(const float4*)(&hpost_sm[row128][0]);
    const float4 h0 = *(const float4*)(&hres_sm[row128][0]);
    const float4 h1 = *(const float4*)(&hres_sm[row128][4]);
    const float4 h2 = *(const float4*)(&hres_sm[row128][8]);
    const float4 h3 = *(const float4*)(&hres_sm[row128][12]);
#pragma unroll
    for (int s = 0; s < 4; ++s) {
      const int c4 = ec + s * 4;          // float4 col 0..15
      float4 y4 = *(const float4*)(&mysc[erow * 68 + c4 * 4]);
      const size_t xb_ = t * 4096 + n0 + wn + c4 * 4;
      float4 x0 = *(const float4*)(x + xb_);
      float4 x1 = *(const float4*)(x + xb_ + 1024);
      float4 x2 = *(const float4*)(x + xb_ + 2048);
      float4 x3 = *(const float4*)(x + xb_ + 3072);
      float4 rr;
      rr.x = x0.x * h0.x + x1.x * h0.y + x2.x * h0.z + x3.x * h0.w + hq.x * y4.x;
      rr.y = x0.y * h0.x + x1.y * h0.y + x2.y * h0.z + x3.y * h0.w + hq.x * y4.y;
      rr.z = x0.z * h0.x + x1.z * h0.y + x2.z * h0.z + x3.z * h0.w + hq.x * y4.z;
      rr.w = x0.w * h0.x + x1.w * h0.y + x2.w * h0.z + x3.w * h0.w + hq.x * y4.w;
      *(float4*)(out + xb_) = rr;
      rr.x = x0.x * h1.x + x1.x * h1.y + x2.x * h1.z + x3.x * h1.w + hq.y * y4.x;
      rr.y = x0.y * h1.x + x1.y * h1.y + x2.y * h1.z + x3.y * h1.w + hq.y * y4.y;
      rr.z = x0.z * h1.x + x1.z * h1.y + x2.z * h1.z + x3.z * h1.w + hq.y * y4.z;
      rr.w = x0.w * h1.x + x1.w * h1.y + x2.w * h1.z + x3.w * h1.w + hq.y * y4.w;
      *(float4*)(out + xb_ + 1024) = rr;
      rr.x = x0.x * h2.x + x1.x * h2.y + x2.x * h2.z + x3.x * h2.w + hq.z * y4.x;
      rr.y = x0.y * h2.x + x1.y * h2.y + x2.y * h2.z + x3.y * h2.w + hq.z * y4.y;
      rr.z = x0.z * h2.x + x1.z * h2.y + x2.z * h2.z + x3.z * h2.w + hq.z * y4.z;
      rr.w = x0.w * h2.x + x1.w * h2.y + x2.w * h2.z + x3.w * h2.w + hq.z * y4.w;
      *(float4*)(out + xb_ + 2048) = rr;
      rr.x = x0.x * h3.x + x1.x * h3.y + x2.x * h3.z + x3.x * h3.w + hq.w * y4.x;
      rr.y = x0.y * h3.x + x1.y * h3.y + x2.y * h3.z + x3.y * h3.w + hq.w * y4.y;
      rr.z = x0.z * h3.x + x1.z * h3.y + x2.z * h3.z + x3.z * h3.w + hq.w * y4.z;
      rr.w = x0.w * h3.x + x1.w * h3.y + x2.w * h3.z + x3.w * h3.w + hq.w * y4.w;
      *(float4*)(out + xb_ + 3072) = rr;
    }
    asm volatile("s_waitcnt lgkmcnt(0)" ::: "memory");  // reads done before next mi's writes
  }
}

extern "C" void kernel_launch(void* const* d_in, const int* in_sizes, int n_in,
                              void* d_out, int out_size, void* d_ws, size_t ws_size,
                              hipStream_t stream) {
  const float* x     = (const float*)d_in[0];
  const float* rms_w = (const float*)d_in[1];
  const float* Wpre  = (const float*)d_in[2];
  const float* Wpost = (const float*)d_in[3];
  const float* Wres  = (const float*)d_in[4];
  const float* bpre  = (const float*)d_in[5];
  const float* bpost = (const float*)d_in[6];
  const float* bres  = (const float*)d_in[7];
  const float* apre  = (const float*)d_in[8];
  const float* apost = (const float*)d_in[9];
  const float* ares  = (const float*)d_in[10];
  const float* Wsub  = (const float*)d_in[11];
  float* out = (float*)d_out;

  char* ws = (char*)d_ws;
  float* gates           = (float*)ws;                         // 640 KB
  unsigned short* Wb     = (unsigned short*)(ws + (1 << 20));  // 2 MB
  unsigned short* Wg     = (unsigned short*)(ws + (3 << 20));  // 256 KB
  unsigned short* xlayer = (unsigned short*)(ws + (4 << 20));  // 16 MB

  prep_kernel<<<2304, 256, 0, stream>>>(Wpre, Wpost, Wres, rms_w, Wsub, Wg, Wb);
  gates_kernel<<<1024, 256, 0, stream>>>(x, Wg, bpre, bpost, bres,
                                         apre, apost, ares, gates, xlayer);
  gemm_epi<<<dim3(8, 64), 256, 0, stream>>>(xlayer, Wb, x, gates, out);
}